// Round 1
// baseline (5470.107 us; speedup 1.0000x reference)
//
#include <hip/hip_runtime.h>

// PGA G(3,0,1) GeometricBilinear, fused fp32 kernel.
// Positions P = B*S = 4*4096 = 16384. CIN=64, 2H=256, H=128, COUT=64, 16 blades.
//
// equi_linear blade structure: for output blade j,
//   h[o,j] = sum_i w[o,i,g(j)] * x[i,j] + (j odd ? sum_i w[o,i,4+g(j)] * x[i,j^1] : 0)
// geometric product: prod[a^b] += sgn(a,b)*l[a]*r[b]  for !(a&b&1)   (192 terms)
// join: prod[a&b] += SA[a]*SA[b]*sgn(~a,~b)*SA[a&b]*l[a]*r[b] for a|b==15 (81 terms),
//       then scale by ref pseudoscalar coeff.  SA[a] = sgn(a, 15^a).

namespace {

constexpr int popc4(int v){int c=0;while(v){c+=v&1;v>>=1;}return c;}
constexpr float sgnf(int a,int b){int s=0;a>>=1;while(a){s+=popc4(a&b);a>>=1;}return (s&1)?-1.f:1.f;}

struct Tabs { float gp[16][16]; float jn[16][16]; };
constexpr Tabs mk(){
    Tabs t{};
    for(int a=0;a<16;a++)for(int b=0;b<16;b++){
        t.gp[a][b] = (a&b&1) ? 0.f : sgnf(a,b);
        if((a|b)==15){
            const int k = a&b;
            t.jn[a][b] = sgnf(a,15^a)*sgnf(b,15^b)*sgnf(15^a,15^b)*sgnf(k,15^k);
        } else t.jn[a][b] = 0.f;
    }
    return t;
}
constexpr Tabs TB = mk();
// grades of even blades j = 0,2,4,6,8,10,12,14
constexpr int GE[8] = {0,1,1,2,1,2,2,3};

} // namespace

// Transpose weights for coalesced loads:
// w1 [256][64][9] -> w1t[(i*9+r)*256 + o];  w2 [64][128][9] -> w2t[(i*9+r)*64 + o]
__global__ void transpose_w(const float* __restrict__ w1, const float* __restrict__ w2,
                            float* __restrict__ w1t, float* __restrict__ w2t)
{
    const int idx = blockIdx.x * 256 + threadIdx.x;
    if (idx < 147456) {
        const int o = idx & 255;
        const int ir = idx >> 8;          // i*9 + r, 0..575
        const int i = ir / 9, r = ir - 9*i;
        w1t[idx] = w1[(o*64 + i)*9 + r];
    } else {
        const int k = idx - 147456;
        if (k < 73728) {
            const int o = k & 63;
            const int ir = k >> 6;        // 0..1151
            const int i = ir / 9, r = ir - 9*i;
            w2t[k] = w2[(o*128 + i)*9 + r];
        }
    }
}

template<bool TW>
__global__ __launch_bounds__(256, 2) void gb_fused(
    const float* __restrict__ x, const float* __restrict__ ref,
    const float* __restrict__ w1, const float* __restrict__ b1,
    const float* __restrict__ w2, const float* __restrict__ b2,
    const float* __restrict__ w1t, const float* __restrict__ w2t,
    float* __restrict__ out)
{
    __shared__ float lds[16384];   // phase1: x tile [8][64][16]; then out2 [8][4][128][4]
    __shared__ float lref[8];
    const int t = threadIdx.x;
    const int p0 = blockIdx.x * 8;

    // ---- stage x tile (8 positions * 1024 floats, contiguous) ----
    {
        const float4* xg = reinterpret_cast<const float4*>(x) + (size_t)p0 * 256;
        float4* xl = reinterpret_cast<float4*>(lds);
        #pragma unroll
        for (int r = 0; r < 8; ++r) xl[r*256 + t] = xg[r*256 + t];
        if (t < 8) lref[t] = ref[(p0 + t)*16 + 15];
    }
    __syncthreads();

    // ---- phase 1: first equi-linear, 2 channels per thread, 4 positions ----
    const int c    = t & 127;       // output-product channel 0..127
    const int half = t >> 7;        // position half
    const int ca   = (c < 64) ? c : (c + 64);   // l_geo ch c  | l_join ch 128+(c-64)
    const int cb   = ca + 64;                   // r_geo ch    | r_join ch

    float acc[4][2][16];
    #pragma unroll
    for (int q = 0; q < 4; ++q)
        #pragma unroll
        for (int s = 0; s < 2; ++s)
            #pragma unroll
            for (int j = 0; j < 16; ++j) acc[q][s][j] = 0.f;

    for (int i = 0; i < 64; ++i) {
        float wa[9], wb[9];
        #pragma unroll
        for (int r = 0; r < 9; ++r) {
            if (TW) {
                wa[r] = w1t[(i*9 + r)*256 + ca];
                wb[r] = w1t[(i*9 + r)*256 + cb];
            } else {
                wa[r] = w1[(ca*64 + i)*9 + r];
                wb[r] = w1[(cb*64 + i)*9 + r];
            }
        }
        #pragma unroll
        for (int q = 0; q < 4; ++q) {
            const float* xv = lds + (half*4 + q)*1024 + i*16;
            float xr[16];
            #pragma unroll
            for (int j4 = 0; j4 < 4; ++j4) {
                const float4 v = *reinterpret_cast<const float4*>(xv + 4*j4);
                xr[4*j4+0]=v.x; xr[4*j4+1]=v.y; xr[4*j4+2]=v.z; xr[4*j4+3]=v.w;
            }
            #pragma unroll
            for (int e = 0; e < 8; ++e) {
                const int ge = GE[e];
                const float xe = xr[2*e], xo = xr[2*e+1];
                acc[q][0][2*e]   += wa[ge]   * xe;
                acc[q][0][2*e+1] += wa[ge+1] * xo;
                acc[q][0][2*e+1] += wa[ge+5] * xe;
                acc[q][1][2*e]   += wb[ge]   * xe;
                acc[q][1][2*e+1] += wb[ge+1] * xo;
                acc[q][1][2*e+1] += wb[ge+5] * xe;
            }
        }
    }
    {
        const float ba = b1[ca], bb = b1[cb];
        #pragma unroll
        for (int q = 0; q < 4; ++q) { acc[q][0][0] += ba; acc[q][1][0] += bb; }
    }

    __syncthreads();   // all x reads complete; lds becomes out2 buffer

    // ---- products (in-register) + out2 -> LDS [pos][j4][ch][4] ----
    #pragma unroll
    for (int q = 0; q < 4; ++q) {
        float prod[16];
        #pragma unroll
        for (int j = 0; j < 16; ++j) prod[j] = 0.f;
        if (c < 64) {
            #pragma unroll
            for (int A = 0; A < 16; ++A)
                #pragma unroll
                for (int B = 0; B < 16; ++B)
                    if (TB.gp[A][B] != 0.f)
                        prod[A ^ B] += TB.gp[A][B] * acc[q][0][A] * acc[q][1][B];
        } else {
            #pragma unroll
            for (int A = 0; A < 16; ++A)
                #pragma unroll
                for (int B = 0; B < 16; ++B)
                    if (TB.jn[A][B] != 0.f)
                        prod[A & B] += TB.jn[A][B] * acc[q][0][A] * acc[q][1][B];
            const float rp = lref[half*4 + q];
            #pragma unroll
            for (int j = 0; j < 16; ++j) prod[j] *= rp;
        }
        const int pos = half*4 + q;
        #pragma unroll
        for (int j4 = 0; j4 < 4; ++j4)
            *reinterpret_cast<float4*>(&lds[(pos*4 + j4)*512 + c*4]) =
                make_float4(prod[4*j4], prod[4*j4+1], prod[4*j4+2], prod[4*j4+3]);
    }
    __syncthreads();

    // ---- phase 2: second equi-linear [128 -> 64], 2 positions per thread ----
    const int o    = t & 63;
    const int slot = t >> 6;
    float oacc[2][16];
    #pragma unroll
    for (int e2 = 0; e2 < 2; ++e2)
        #pragma unroll
        for (int j = 0; j < 16; ++j) oacc[e2][j] = 0.f;

    for (int i = 0; i < 128; ++i) {
        float wv[9];
        #pragma unroll
        for (int r = 0; r < 9; ++r) {
            if (TW) wv[r] = w2t[(i*9 + r)*64 + o];
            else    wv[r] = w2[(o*128 + i)*9 + r];
        }
        #pragma unroll
        for (int e2 = 0; e2 < 2; ++e2) {
            const int pos = slot*2 + e2;
            float xr[16];
            #pragma unroll
            for (int j4 = 0; j4 < 4; ++j4) {
                const float4 v = *reinterpret_cast<const float4*>(&lds[(pos*4 + j4)*512 + i*4]);
                xr[4*j4+0]=v.x; xr[4*j4+1]=v.y; xr[4*j4+2]=v.z; xr[4*j4+3]=v.w;
            }
            #pragma unroll
            for (int e = 0; e < 8; ++e) {
                const int ge = GE[e];
                oacc[e2][2*e]   += wv[ge]   * xr[2*e];
                oacc[e2][2*e+1] += wv[ge+1] * xr[2*e+1];
                oacc[e2][2*e+1] += wv[ge+5] * xr[2*e];
            }
        }
    }
    {
        const float bo = b2[o];
        #pragma unroll
        for (int e2 = 0; e2 < 2; ++e2) {
            oacc[e2][0] += bo;
            const int pos = p0 + slot*2 + e2;
            float* og = out + (size_t)pos*1024 + o*16;
            #pragma unroll
            for (int j4 = 0; j4 < 4; ++j4)
                *reinterpret_cast<float4*>(og + 4*j4) =
                    make_float4(oacc[e2][4*j4], oacc[e2][4*j4+1],
                                oacc[e2][4*j4+2], oacc[e2][4*j4+3]);
        }
    }
}

extern "C" void kernel_launch(void* const* d_in, const int* in_sizes, int n_in,
                              void* d_out, int out_size, void* d_ws, size_t ws_size,
                              hipStream_t stream)
{
    const float* x  = (const float*)d_in[0];
    const float* rf = (const float*)d_in[1];
    const float* w1 = (const float*)d_in[2];
    const float* b1 = (const float*)d_in[3];
    const float* w2 = (const float*)d_in[4];
    const float* b2 = (const float*)d_in[5];
    float* out = (float*)d_out;

    const size_t need = (size_t)(147456 + 73728) * sizeof(float);
    if (ws_size >= need) {
        float* w1t = (float*)d_ws;
        float* w2t = w1t + 147456;
        transpose_w<<<864, 256, 0, stream>>>(w1, w2, w1t, w2t);
        gb_fused<true><<<2048, 256, 0, stream>>>(x, rf, w1, b1, w2, b2, w1t, w2t, out);
    } else {
        gb_fused<false><<<2048, 256, 0, stream>>>(x, rf, w1, b1, w2, b2, nullptr, nullptr, out);
    }
}

// Round 3
// 429.685 us; speedup vs baseline: 12.7305x; 12.7305x over previous
//
#include <hip/hip_runtime.h>

// PGA G(3,0,1) GeometricBilinear, fused fp32 kernel.
// Positions P = B*S = 4*4096 = 16384. CIN=64, 2H=256, H=128, COUT=64, 16 blades.
//
// R1 change: __launch_bounds__(256,1) — R0's (256,2) capped VGPRs at 128,
// spilling the 128-float phase-1 accumulator to scratch (16.5 GB of HBM
// writes observed). LDS (66KB) limits us to 2 blocks/CU anyway, which the
// ~200-VGPR allocation also permits (2 waves/SIMD).
// R2: identical resubmit — R1 bench died on container infra, no data.

namespace {

constexpr int popc4(int v){int c=0;while(v){c+=v&1;v>>=1;}return c;}
constexpr float sgnf(int a,int b){int s=0;a>>=1;while(a){s+=popc4(a&b);a>>=1;}return (s&1)?-1.f:1.f;}

struct Tabs { float gp[16][16]; float jn[16][16]; };
constexpr Tabs mk(){
    Tabs t{};
    for(int a=0;a<16;a++)for(int b=0;b<16;b++){
        t.gp[a][b] = (a&b&1) ? 0.f : sgnf(a,b);
        if((a|b)==15){
            const int k = a&b;
            t.jn[a][b] = sgnf(a,15^a)*sgnf(b,15^b)*sgnf(15^a,15^b)*sgnf(k,15^k);
        } else t.jn[a][b] = 0.f;
    }
    return t;
}
constexpr Tabs TB = mk();
// grades of even blades j = 0,2,4,6,8,10,12,14
constexpr int GE[8] = {0,1,1,2,1,2,2,3};

} // namespace

// Transpose weights for coalesced loads:
// w1 [256][64][9] -> w1t[(i*9+r)*256 + o];  w2 [64][128][9] -> w2t[(i*9+r)*64 + o]
__global__ void transpose_w(const float* __restrict__ w1, const float* __restrict__ w2,
                            float* __restrict__ w1t, float* __restrict__ w2t)
{
    const int idx = blockIdx.x * 256 + threadIdx.x;
    if (idx < 147456) {
        const int o = idx & 255;
        const int ir = idx >> 8;          // i*9 + r, 0..575
        const int i = ir / 9, r = ir - 9*i;
        w1t[idx] = w1[(o*64 + i)*9 + r];
    } else {
        const int k = idx - 147456;
        if (k < 73728) {
            const int o = k & 63;
            const int ir = k >> 6;        // 0..1151
            const int i = ir / 9, r = ir - 9*i;
            w2t[k] = w2[(o*128 + i)*9 + r];
        }
    }
}

template<bool TW>
__global__ __launch_bounds__(256, 1) void gb_fused(
    const float* __restrict__ x, const float* __restrict__ ref,
    const float* __restrict__ w1, const float* __restrict__ b1,
    const float* __restrict__ w2, const float* __restrict__ b2,
    const float* __restrict__ w1t, const float* __restrict__ w2t,
    float* __restrict__ out)
{
    __shared__ float lds[16384];   // phase1: x tile [8][64][16]; then out2 [8][4][128][4]
    __shared__ float lref[8];
    const int t = threadIdx.x;
    const int p0 = blockIdx.x * 8;

    // ---- stage x tile (8 positions * 1024 floats, contiguous) ----
    {
        const float4* xg = reinterpret_cast<const float4*>(x) + (size_t)p0 * 256;
        float4* xl = reinterpret_cast<float4*>(lds);
        #pragma unroll
        for (int r = 0; r < 8; ++r) xl[r*256 + t] = xg[r*256 + t];
        if (t < 8) lref[t] = ref[(p0 + t)*16 + 15];
    }
    __syncthreads();

    // ---- phase 1: first equi-linear, 2 channels per thread, 4 positions ----
    const int c    = t & 127;       // output-product channel 0..127
    const int half = t >> 7;        // position half
    const int ca   = (c < 64) ? c : (c + 64);   // l_geo ch c  | l_join ch 128+(c-64)
    const int cb   = ca + 64;                   // r_geo ch    | r_join ch

    float acc[4][2][16];
    #pragma unroll
    for (int q = 0; q < 4; ++q)
        #pragma unroll
        for (int s = 0; s < 2; ++s)
            #pragma unroll
            for (int j = 0; j < 16; ++j) acc[q][s][j] = 0.f;

    for (int i = 0; i < 64; ++i) {
        float wa[9], wb[9];
        #pragma unroll
        for (int r = 0; r < 9; ++r) {
            if (TW) {
                wa[r] = w1t[(i*9 + r)*256 + ca];
                wb[r] = w1t[(i*9 + r)*256 + cb];
            } else {
                wa[r] = w1[(ca*64 + i)*9 + r];
                wb[r] = w1[(cb*64 + i)*9 + r];
            }
        }
        #pragma unroll
        for (int q = 0; q < 4; ++q) {
            const float* xv = lds + (half*4 + q)*1024 + i*16;
            float xr[16];
            #pragma unroll
            for (int j4 = 0; j4 < 4; ++j4) {
                const float4 v = *reinterpret_cast<const float4*>(xv + 4*j4);
                xr[4*j4+0]=v.x; xr[4*j4+1]=v.y; xr[4*j4+2]=v.z; xr[4*j4+3]=v.w;
            }
            #pragma unroll
            for (int e = 0; e < 8; ++e) {
                const int ge = GE[e];
                const float xe = xr[2*e], xo = xr[2*e+1];
                acc[q][0][2*e]   += wa[ge]   * xe;
                acc[q][0][2*e+1] += wa[ge+1] * xo;
                acc[q][0][2*e+1] += wa[ge+5] * xe;
                acc[q][1][2*e]   += wb[ge]   * xe;
                acc[q][1][2*e+1] += wb[ge+1] * xo;
                acc[q][1][2*e+1] += wb[ge+5] * xe;
            }
        }
    }
    {
        const float ba = b1[ca], bb = b1[cb];
        #pragma unroll
        for (int q = 0; q < 4; ++q) { acc[q][0][0] += ba; acc[q][1][0] += bb; }
    }

    __syncthreads();   // all x reads complete; lds becomes out2 buffer

    // ---- products (in-register) + out2 -> LDS [pos][j4][ch][4] ----
    #pragma unroll
    for (int q = 0; q < 4; ++q) {
        float prod[16];
        #pragma unroll
        for (int j = 0; j < 16; ++j) prod[j] = 0.f;
        if (c < 64) {
            #pragma unroll
            for (int A = 0; A < 16; ++A)
                #pragma unroll
                for (int B = 0; B < 16; ++B)
                    if (TB.gp[A][B] != 0.f)
                        prod[A ^ B] += TB.gp[A][B] * acc[q][0][A] * acc[q][1][B];
        } else {
            #pragma unroll
            for (int A = 0; A < 16; ++A)
                #pragma unroll
                for (int B = 0; B < 16; ++B)
                    if (TB.jn[A][B] != 0.f)
                        prod[A & B] += TB.jn[A][B] * acc[q][0][A] * acc[q][1][B];
            const float rp = lref[half*4 + q];
            #pragma unroll
            for (int j = 0; j < 16; ++j) prod[j] *= rp;
        }
        const int pos = half*4 + q;
        #pragma unroll
        for (int j4 = 0; j4 < 4; ++j4)
            *reinterpret_cast<float4*>(&lds[(pos*4 + j4)*512 + c*4]) =
                make_float4(prod[4*j4], prod[4*j4+1], prod[4*j4+2], prod[4*j4+3]);
    }
    __syncthreads();

    // ---- phase 2: second equi-linear [128 -> 64], 2 positions per thread ----
    const int o    = t & 63;
    const int slot = t >> 6;
    float oacc[2][16];
    #pragma unroll
    for (int e2 = 0; e2 < 2; ++e2)
        #pragma unroll
        for (int j = 0; j < 16; ++j) oacc[e2][j] = 0.f;

    for (int i = 0; i < 128; ++i) {
        float wv[9];
        #pragma unroll
        for (int r = 0; r < 9; ++r) {
            if (TW) wv[r] = w2t[(i*9 + r)*64 + o];
            else    wv[r] = w2[(o*128 + i)*9 + r];
        }
        #pragma unroll
        for (int e2 = 0; e2 < 2; ++e2) {
            const int pos = slot*2 + e2;
            float xr[16];
            #pragma unroll
            for (int j4 = 0; j4 < 4; ++j4) {
                const float4 v = *reinterpret_cast<const float4*>(&lds[(pos*4 + j4)*512 + i*4]);
                xr[4*j4+0]=v.x; xr[4*j4+1]=v.y; xr[4*j4+2]=v.z; xr[4*j4+3]=v.w;
            }
            #pragma unroll
            for (int e = 0; e < 8; ++e) {
                const int ge = GE[e];
                oacc[e2][2*e]   += wv[ge]   * xr[2*e];
                oacc[e2][2*e+1] += wv[ge+1] * xr[2*e+1];
                oacc[e2][2*e+1] += wv[ge+5] * xr[2*e];
            }
        }
    }
    {
        const float bo = b2[o];
        #pragma unroll
        for (int e2 = 0; e2 < 2; ++e2) {
            oacc[e2][0] += bo;
            const int pos = p0 + slot*2 + e2;
            float* og = out + (size_t)pos*1024 + o*16;
            #pragma unroll
            for (int j4 = 0; j4 < 4; ++j4)
                *reinterpret_cast<float4*>(og + 4*j4) =
                    make_float4(oacc[e2][4*j4], oacc[e2][4*j4+1],
                                oacc[e2][4*j4+2], oacc[e2][4*j4+3]);
        }
    }
}

extern "C" void kernel_launch(void* const* d_in, const int* in_sizes, int n_in,
                              void* d_out, int out_size, void* d_ws, size_t ws_size,
                              hipStream_t stream)
{
    const float* x  = (const float*)d_in[0];
    const float* rf = (const float*)d_in[1];
    const float* w1 = (const float*)d_in[2];
    const float* b1 = (const float*)d_in[3];
    const float* w2 = (const float*)d_in[4];
    const float* b2 = (const float*)d_in[5];
    float* out = (float*)d_out;

    const size_t need = (size_t)(147456 + 73728) * sizeof(float);
    if (ws_size >= need) {
        float* w1t = (float*)d_ws;
        float* w2t = w1t + 147456;
        transpose_w<<<864, 256, 0, stream>>>(w1, w2, w1t, w2t);
        gb_fused<true><<<2048, 256, 0, stream>>>(x, rf, w1, b1, w2, b2, w1t, w2t, out);
    } else {
        gb_fused<false><<<2048, 256, 0, stream>>>(x, rf, w1, b1, w2, b2, nullptr, nullptr, out);
    }
}

// Round 4
// 175.784 us; speedup vs baseline: 31.1184x; 2.4444x over previous
//
#include <hip/hip_runtime.h>

// PGA G(3,0,1) GeometricBilinear — bf16 MFMA version.
// P = 16384 positions. CIN=64, 2H=256, H=128, COUT=64, 16 blades.
//
// Reformulation: blade-pair packing. For pair e (blades 2e, 2e+1):
//   A_e[p, k] (K=128), k = s*64 + i  ->  x[p, i, 2e+s]   (bf16, LDS, XOR-swizzled)
// Blade j=2e   (even): h[p,o,j] = sum_{k<64}  Wj[o,k] A_e[p,k]   (K=64)
// Blade j=2e+1 (odd):  h[p,o,j] = sum_{k<128} Wj[o,k] A_e[p,k]   (K=128)
// with packed weights (bf16, in d_ws):
//   even j: Wj[o,k] = w1[o,k,g(j)]
//   odd  j: k<64 -> w1[o,k,g(j)+4] ; k>=64 -> w1[o,k-64,g(j)]   (g = popcount)
// MFMA 16x16x32: A = Wj (m=o), B = A_e (n=pos), D: col(l&15)=pos, row((l>>4)*4+r)=o.
// 8 waves = 8 of-pairs (f, f+4), f in {0..3, 8..11}: each lane then holds BOTH
// h[c] and h[c+64] for its 4 product channels -> GP/join fully in-register.
// prod -> LDS (bf16, k2 = s*128 + cc, swizzled) -> phase-2 MFMA -> fp32 out.

namespace {

constexpr int popc4(int v){int c=0;while(v){c+=v&1;v>>=1;}return c;}
constexpr float sgnf(int a,int b){int s=0;a>>=1;while(a){s+=popc4(a&b);a>>=1;}return (s&1)?-1.f:1.f;}

struct Tabs { float gp[16][16]; float jn[16][16]; };
constexpr Tabs mk(){
    Tabs t{};
    for(int a=0;a<16;a++)for(int b=0;b<16;b++){
        t.gp[a][b] = (a&b&1) ? 0.f : sgnf(a,b);
        if((a|b)==15){
            const int k = a&b;
            t.jn[a][b] = sgnf(a,15^a)*sgnf(b,15^b)*sgnf(15^a,15^b)*sgnf(k,15^k);
        } else t.jn[a][b] = 0.f;
    }
    return t;
}
constexpr Tabs TB = mk();
constexpr int GE[8] = {0,1,1,2,1,2,2,3};  // grade of even blade 2e (fallback kernel)

// packed-weight offsets (bf16 units)
constexpr int OFF1(int j){ return (j>>1)*49152 + ((j&1)?16384:0); }   // w1b: even 256*64, odd 256*128
constexpr int OFF2(int j){ return (j>>1)*24576 + ((j&1)?8192:0);  }   // w2b: even 64*128, odd 64*256
constexpr int W1B_ELEMS = 393216;   // 786,432 B
constexpr int W2B_ELEMS = 196608;   // 393,216 B

typedef short bf16x8 __attribute__((ext_vector_type(8)));
typedef float f32x4  __attribute__((ext_vector_type(4)));

__device__ inline unsigned short f2bf(float f){
    unsigned int u = __float_as_uint(f);
    u = u + 0x7fffu + ((u >> 16) & 1u);     // round-to-nearest-even
    return (unsigned short)(u >> 16);
}

} // namespace

// ---------------- weight prep: pack w1,w2 (fp32, [o][i][9]) -> bf16 tables ----
__global__ void prep_w(const float* __restrict__ w1, const float* __restrict__ w2,
                       unsigned short* __restrict__ w1b, unsigned short* __restrict__ w2b)
{
    int idx = blockIdx.x * 256 + threadIdx.x;
    if (idx < W1B_ELEMS) {
        const int p = idx / 49152, rem = idx - p*49152;
        float v;
        if (rem < 16384) {                       // even j: [256 o][64 k]
            const int j = 2*p, o = rem >> 6, k = rem & 63;
            v = w1[(o*64 + k)*9 + __popc(j)];
        } else {                                 // odd j: [256 o][128 k]
            const int j = 2*p + 1, r2 = rem - 16384, o = r2 >> 7, k = r2 & 127;
            const int g = __popc(j), i = k & 63, r = (k < 64) ? g + 4 : g;
            v = w1[(o*64 + i)*9 + r];
        }
        w1b[idx] = f2bf(v);
    } else {
        idx -= W1B_ELEMS;
        if (idx < W2B_ELEMS) {
            const int p = idx / 24576, rem = idx - p*24576;
            float v;
            if (rem < 8192) {                    // even j: [64 o][128 k]
                const int j = 2*p, o = rem >> 7, k = rem & 127;
                v = w2[(o*128 + k)*9 + __popc(j)];
            } else {                             // odd j: [64 o][256 k]
                const int j = 2*p + 1, r2 = rem - 8192, o = r2 >> 8, k = r2 & 255;
                const int g = __popc(j), i = k & 127, r = (k < 128) ? g + 4 : g;
                v = w2[(o*128 + i)*9 + r];
            }
            w2b[idx] = f2bf(v);
        }
    }
}

// ---------------- fused MFMA kernel: 16 positions / block, 8 waves -----------
__global__ __launch_bounds__(512, 2) void gb_mfma(
    const float* __restrict__ x, const float* __restrict__ ref,
    const float* __restrict__ b1, const float* __restrict__ b2,
    const unsigned short* __restrict__ w1b, const unsigned short* __restrict__ w2b,
    float* __restrict__ out)
{
    __shared__ __attribute__((aligned(16))) char lds[65536]; // X1: 32KB, then X2: 64KB
    __shared__ float lref[16];

    const int t  = threadIdx.x;
    const int p0 = blockIdx.x * 16;
    const int w  = t >> 6;
    const int l  = t & 63;
    const int ln = l & 15;
    const int lh = l >> 4;
    const int swz = (ln & 7) << 4;

    // ---- stage X1: x[p0..p0+15][64][16] fp32 -> bf16 LDS [e][pos][k=s*64+i] --
    {
        const float4* xg = reinterpret_cast<const float4*>(x + (size_t)p0 * 1024);
        #pragma unroll
        for (int it = 0; it < 8; ++it) {
            const int idx = it*512 + t;           // 4096 float4s
            const float4 v = xg[idx];
            const int pos = idx >> 8, rem = idx & 255;
            const int i = rem >> 2, c = rem & 3;
            const int ws_ = (pos & 7) << 4;
            const int rowA = (2*c)   * 16 + pos;  // e = 2c
            const int rowB = (2*c+1) * 16 + pos;  // e = 2c+1
            *(unsigned short*)(lds + (((rowA<<8) + ((i)<<1))      ^ ws_)) = f2bf(v.x); // s=0
            *(unsigned short*)(lds + (((rowA<<8) + ((64+i)<<1))   ^ ws_)) = f2bf(v.y); // s=1
            *(unsigned short*)(lds + (((rowB<<8) + ((i)<<1))      ^ ws_)) = f2bf(v.z);
            *(unsigned short*)(lds + (((rowB<<8) + ((64+i)<<1))   ^ ws_)) = f2bf(v.w);
        }
        if (t < 16) lref[t] = ref[(size_t)(p0 + t)*16 + 15];
    }
    __syncthreads();

    // ---- phase 1: h fragments for of-pair (f, f+4) ----
    const int f0 = (w < 4) ? w : w + 4;
    const int oA = f0*16 + ln;          // A-frag row (o), lo half of pair
    const int oB = (f0+4)*16 + ln;      // hi half (+64 channels)

    f32x4 acc[16][2];
    #pragma unroll
    for (int j = 0; j < 16; ++j) { acc[j][0] = (f32x4)0.f; acc[j][1] = (f32x4)0.f; }

    #pragma unroll
    for (int j = 0; j < 16; ++j) {
        const int e  = j >> 1;
        const int Kj = (j & 1) ? 128 : 64;
        const unsigned short* Aj = w1b + OFF1(j);
        #pragma unroll
        for (int kf = 0; kf < ((j & 1) ? 4 : 2); ++kf) {
            const int k0 = kf*32 + lh*8;
            const bf16x8 bx = *(const bf16x8*)(lds + ((((e*16 + ln) << 8) + (k0 << 1)) ^ swz));
            const bf16x8 a0 = *(const bf16x8*)(Aj + oA*Kj + k0);
            const bf16x8 a1 = *(const bf16x8*)(Aj + oB*Kj + k0);
            acc[j][0] = __builtin_amdgcn_mfma_f32_16x16x32_bf16(a0, bx, acc[j][0], 0, 0, 0);
            acc[j][1] = __builtin_amdgcn_mfma_f32_16x16x32_bf16(a1, bx, acc[j][1], 0, 0, 0);
        }
    }
    // bias on scalar blade (j=0)
    {
        #pragma unroll
        for (int r = 0; r < 4; ++r) {
            acc[0][0][r] += b1[f0*16     + lh*4 + r];
            acc[0][1][r] += b1[(f0+4)*16 + lh*4 + r];
        }
    }

    // ---- products, fully in-register (lane: pos=ln, 4 channels = lh*4+r) ----
    f32x4 prod[16];
    #pragma unroll
    for (int j = 0; j < 16; ++j) prod[j] = (f32x4)0.f;
    if (w < 4) {
        #pragma unroll
        for (int A = 0; A < 16; ++A)
            #pragma unroll
            for (int B = 0; B < 16; ++B) {
                constexpr auto& G = TB.gp;
                if (G[A][B] > 0.f)      prod[A ^ B] += acc[A][0] * acc[B][1];
                else if (G[A][B] < 0.f) prod[A ^ B] -= acc[A][0] * acc[B][1];
            }
    } else {
        #pragma unroll
        for (int A = 0; A < 16; ++A)
            #pragma unroll
            for (int B = 0; B < 16; ++B) {
                constexpr auto& J = TB.jn;
                if (J[A][B] > 0.f)      prod[A & B] += acc[A][0] * acc[B][1];
                else if (J[A][B] < 0.f) prod[A & B] -= acc[A][0] * acc[B][1];
            }
        const float rv = lref[ln];
        #pragma unroll
        for (int j = 0; j < 16; ++j) prod[j] *= rv;
    }

    __syncthreads();   // all X1 reads done; lds becomes X2 [e][pos][k2=s*128+cc]

    // ---- write prod -> X2 (bf16, swizzled) ----
    {
        const int pc0 = (w < 4) ? w*16 : 64 + (w - 4)*16;
        #pragma unroll
        for (int e2 = 0; e2 < 8; ++e2) {
            #pragma unroll
            for (int r = 0; r < 4; ++r) {
                const int cc = pc0 + lh*4 + r;
                const int byte0 = ((((e2*16 + ln) << 9) + (cc << 1)) ^ swz);
                *(unsigned short*)(lds + byte0)       = f2bf(prod[2*e2][r]);     // s=0
                *(unsigned short*)(lds + byte0 + 256) = f2bf(prod[2*e2+1][r]);   // s=1
            }
        }
    }
    __syncthreads();

    // ---- phase 2: out[o2, j] — wave: jh = w>>2 (8 blades), of2 = w&3 ----
    const int jh = w >> 2;
    const int o2base = (w & 3) * 16;
    f32x4 acc2[8];
    #pragma unroll
    for (int jj = 0; jj < 8; ++jj) acc2[jj] = (f32x4)0.f;

    #pragma unroll
    for (int jj = 0; jj < 8; ++jj) {
        const int j2 = jh*8 + jj;
        const int e2 = j2 >> 1;
        const int K2 = (j2 & 1) ? 256 : 128;
        const unsigned short* A2 = w2b + OFF2(j2);
        #pragma unroll
        for (int kf = 0; kf < ((j2 & 1) ? 8 : 4); ++kf) {
            const int k0 = kf*32 + lh*8;
            const bf16x8 bx = *(const bf16x8*)(lds + ((((e2*16 + ln) << 9) + (k0 << 1)) ^ swz));
            const bf16x8 a  = *(const bf16x8*)(A2 + (o2base + ln)*K2 + k0);
            acc2[jj] = __builtin_amdgcn_mfma_f32_16x16x32_bf16(a, bx, acc2[jj], 0, 0, 0);
        }
    }
    if (jh == 0) {
        #pragma unroll
        for (int r = 0; r < 4; ++r) acc2[0][r] += b2[o2base + lh*4 + r];
    }
    // store: lane pos=ln, o2 = o2base + lh*4 + r, blades jh*8 + (0..7)
    {
        float* ob = out + (size_t)(p0 + ln)*1024 + jh*8;
        #pragma unroll
        for (int r = 0; r < 4; ++r) {
            const int o2 = o2base + lh*4 + r;
            float4 v0 = make_float4(acc2[0][r], acc2[1][r], acc2[2][r], acc2[3][r]);
            float4 v1 = make_float4(acc2[4][r], acc2[5][r], acc2[6][r], acc2[7][r]);
            *reinterpret_cast<float4*>(ob + o2*16)     = v0;
            *reinterpret_cast<float4*>(ob + o2*16 + 4) = v1;
        }
    }
}

// ---------------- fp32 fallback (verified R3 structure, direct-w path) -------
__global__ __launch_bounds__(256, 1) void gb_fused_f32(
    const float* __restrict__ x, const float* __restrict__ ref,
    const float* __restrict__ w1, const float* __restrict__ b1,
    const float* __restrict__ w2, const float* __restrict__ b2,
    float* __restrict__ out)
{
    __shared__ float lds[16384];
    __shared__ float lrefs[8];
    const int t = threadIdx.x;
    const int p0 = blockIdx.x * 8;
    {
        const float4* xg = reinterpret_cast<const float4*>(x) + (size_t)p0 * 256;
        float4* xl = reinterpret_cast<float4*>(lds);
        #pragma unroll
        for (int r = 0; r < 8; ++r) xl[r*256 + t] = xg[r*256 + t];
        if (t < 8) lrefs[t] = ref[(p0 + t)*16 + 15];
    }
    __syncthreads();
    const int c    = t & 127;
    const int half = t >> 7;
    const int ca   = (c < 64) ? c : (c + 64);
    const int cb   = ca + 64;
    float acc[4][2][16];
    #pragma unroll
    for (int q = 0; q < 4; ++q)
        #pragma unroll
        for (int s = 0; s < 2; ++s)
            #pragma unroll
            for (int j = 0; j < 16; ++j) acc[q][s][j] = 0.f;
    for (int i = 0; i < 64; ++i) {
        float wa[9], wb[9];
        #pragma unroll
        for (int r = 0; r < 9; ++r) { wa[r] = w1[(ca*64+i)*9 + r]; wb[r] = w1[(cb*64+i)*9 + r]; }
        #pragma unroll
        for (int q = 0; q < 4; ++q) {
            const float* xv = lds + (half*4 + q)*1024 + i*16;
            float xr[16];
            #pragma unroll
            for (int j4 = 0; j4 < 4; ++j4) {
                const float4 v = *reinterpret_cast<const float4*>(xv + 4*j4);
                xr[4*j4+0]=v.x; xr[4*j4+1]=v.y; xr[4*j4+2]=v.z; xr[4*j4+3]=v.w;
            }
            #pragma unroll
            for (int e = 0; e < 8; ++e) {
                const int ge = GE[e];
                const float xe = xr[2*e], xo = xr[2*e+1];
                acc[q][0][2*e]   += wa[ge]   * xe;
                acc[q][0][2*e+1] += wa[ge+1] * xo;
                acc[q][0][2*e+1] += wa[ge+5] * xe;
                acc[q][1][2*e]   += wb[ge]   * xe;
                acc[q][1][2*e+1] += wb[ge+1] * xo;
                acc[q][1][2*e+1] += wb[ge+5] * xe;
            }
        }
    }
    {
        const float ba = b1[ca], bb = b1[cb];
        #pragma unroll
        for (int q = 0; q < 4; ++q) { acc[q][0][0] += ba; acc[q][1][0] += bb; }
    }
    __syncthreads();
    #pragma unroll
    for (int q = 0; q < 4; ++q) {
        float prod[16];
        #pragma unroll
        for (int j = 0; j < 16; ++j) prod[j] = 0.f;
        if (c < 64) {
            #pragma unroll
            for (int A = 0; A < 16; ++A)
                #pragma unroll
                for (int B = 0; B < 16; ++B)
                    if (TB.gp[A][B] != 0.f)
                        prod[A ^ B] += TB.gp[A][B] * acc[q][0][A] * acc[q][1][B];
        } else {
            #pragma unroll
            for (int A = 0; A < 16; ++A)
                #pragma unroll
                for (int B = 0; B < 16; ++B)
                    if (TB.jn[A][B] != 0.f)
                        prod[A & B] += TB.jn[A][B] * acc[q][0][A] * acc[q][1][B];
            const float rp = lrefs[half*4 + q];
            #pragma unroll
            for (int j = 0; j < 16; ++j) prod[j] *= rp;
        }
        const int pos = half*4 + q;
        #pragma unroll
        for (int j4 = 0; j4 < 4; ++j4)
            *reinterpret_cast<float4*>(&lds[(pos*4 + j4)*512 + c*4]) =
                make_float4(prod[4*j4], prod[4*j4+1], prod[4*j4+2], prod[4*j4+3]);
    }
    __syncthreads();
    const int o    = t & 63;
    const int slot = t >> 6;
    float oacc[2][16];
    #pragma unroll
    for (int e2 = 0; e2 < 2; ++e2)
        #pragma unroll
        for (int j = 0; j < 16; ++j) oacc[e2][j] = 0.f;
    for (int i = 0; i < 128; ++i) {
        float wv[9];
        #pragma unroll
        for (int r = 0; r < 9; ++r) wv[r] = w2[(o*128+i)*9 + r];
        #pragma unroll
        for (int e2 = 0; e2 < 2; ++e2) {
            const int pos = slot*2 + e2;
            float xr[16];
            #pragma unroll
            for (int j4 = 0; j4 < 4; ++j4) {
                const float4 v = *reinterpret_cast<const float4*>(&lds[(pos*4 + j4)*512 + i*4]);
                xr[4*j4+0]=v.x; xr[4*j4+1]=v.y; xr[4*j4+2]=v.z; xr[4*j4+3]=v.w;
            }
            #pragma unroll
            for (int e = 0; e < 8; ++e) {
                const int ge = GE[e];
                oacc[e2][2*e]   += wv[ge]   * xr[2*e];
                oacc[e2][2*e+1] += wv[ge+1] * xr[2*e+1];
                oacc[e2][2*e+1] += wv[ge+5] * xr[2*e];
            }
        }
    }
    {
        const float bo = b2[o];
        #pragma unroll
        for (int e2 = 0; e2 < 2; ++e2) {
            oacc[e2][0] += bo;
            const int pos = p0 + slot*2 + e2;
            float* og = out + (size_t)pos*1024 + o*16;
            #pragma unroll
            for (int j4 = 0; j4 < 4; ++j4)
                *reinterpret_cast<float4*>(og + 4*j4) =
                    make_float4(oacc[e2][4*j4], oacc[e2][4*j4+1],
                                oacc[e2][4*j4+2], oacc[e2][4*j4+3]);
        }
    }
}

extern "C" void kernel_launch(void* const* d_in, const int* in_sizes, int n_in,
                              void* d_out, int out_size, void* d_ws, size_t ws_size,
                              hipStream_t stream)
{
    const float* x  = (const float*)d_in[0];
    const float* rf = (const float*)d_in[1];
    const float* w1 = (const float*)d_in[2];
    const float* b1 = (const float*)d_in[3];
    const float* w2 = (const float*)d_in[4];
    const float* b2 = (const float*)d_in[5];
    float* out = (float*)d_out;

    const size_t need = (size_t)(W1B_ELEMS + W2B_ELEMS) * sizeof(unsigned short);
    if (ws_size >= need) {
        unsigned short* w1b = (unsigned short*)d_ws;
        unsigned short* w2b = w1b + W1B_ELEMS;
        prep_w<<<(W1B_ELEMS + W2B_ELEMS)/256, 256, 0, stream>>>(w1, w2, w1b, w2b);
        gb_mfma<<<1024, 512, 0, stream>>>(x, rf, b1, b2, w1b, w2b, out);
    } else {
        gb_fused_f32<<<2048, 256, 0, stream>>>(x, rf, w1, b1, w2, b2, out);
    }
}